// Round 11
// baseline (1433.151 us; speedup 1.0000x reference)
//
#include <hip/hip_runtime.h>
#include <hip/hip_bf16.h>
#include <stdint.h>

// Problem constants
#define NHEAD 8
#define DMODEL 512
#define DVOCAB 32000
#define M_DIM 4096            // B*P
#define K_DIM 4096            // NHEAD*DMODEL
#define N_DIM 32000           // DVOCAB
#define NKT   128             // K_DIM / 32 k-tiles

typedef short bf16x8 __attribute__((ext_vector_type(8)));
typedef float f32x4 __attribute__((ext_vector_type(4)));
typedef unsigned short ushort8 __attribute__((ext_vector_type(8)));

template <int V> struct IC { static constexpr int v = V; };

__device__ __forceinline__ unsigned short f2bf(float f) {
    unsigned int u = __builtin_bit_cast(unsigned int, f);
    u = (u + 0x7fffu + ((u >> 16) & 1u)) >> 16;   // RNE (inputs are finite)
    return (unsigned short)u;
}

__device__ __forceinline__ void load16_to_lds(const void* g, void* l) {
    __builtin_amdgcn_global_load_lds(
        (const __attribute__((address_space(1))) unsigned int*)g,
        (__attribute__((address_space(3))) unsigned int*)l, 16, 0, 0);
}

// ---- x [4096][4096] f32 -> bf16, 8 elems/thread ----
__global__ void cvt_x(const float* __restrict__ in, unsigned short* __restrict__ out) {
    long t = (long)blockIdx.x * 256 + threadIdx.x;
    const float4* s = (const float4*)in + t * 2;
    float4 a = s[0], b = s[1];
    ushort8 o;
    o[0] = f2bf(a.x); o[1] = f2bf(a.y); o[2] = f2bf(a.z); o[3] = f2bf(a.w);
    o[4] = f2bf(b.x); o[5] = f2bf(b.y); o[6] = f2bf(b.z); o[7] = f2bf(b.w);
    *(ushort8*)(out + t * 8) = o;
}

// ---- W [H][V][D] f32 -> Wb [V][H*D] bf16 (B^T layout), 8 elems/thread ----
__global__ void cvt_w(const float* __restrict__ in, unsigned short* __restrict__ out) {
    int t = blockIdx.x * 256 + threadIdx.x;
    int d8 = t & 63;
    int hv = t >> 6;
    int h = hv / DVOCAB;
    int v = hv - h * DVOCAB;
    const float4* s = (const float4*)(in + (long)hv * DMODEL + d8 * 8);
    float4 a = s[0], b = s[1];
    ushort8 o;
    o[0] = f2bf(a.x); o[1] = f2bf(a.y); o[2] = f2bf(a.z); o[3] = f2bf(a.w);
    o[4] = f2bf(b.x); o[5] = f2bf(b.y); o[6] = f2bf(b.z); o[7] = f2bf(b.w);
    *(ushort8*)(out + (long)v * K_DIM + h * DMODEL + d8 * 8) = o;
}

// ---- bias [H][V] -> bsum [V] ----
__global__ void bias_red(const float* __restrict__ b, float* __restrict__ out) {
    int v = blockIdx.x * 256 + threadIdx.x;
    if (v >= DVOCAB) return;
    float s = 0.f;
    #pragma unroll
    for (int h = 0; h < NHEAD; ++h) s += b[h * DVOCAB + v];
    out[v] = s;
}

#define BAR()    __builtin_amdgcn_s_barrier()
#define VMCNT8() asm volatile("s_waitcnt vmcnt(8)" ::: "memory")
#define VMCNT4() asm volatile("s_waitcnt vmcnt(4)" ::: "memory")
#define VMCNT0() asm volatile("s_waitcnt vmcnt(0)" ::: "memory")

// ---- bf16 GEMM, 128x128 tile, BK=32, ring-4 LDS, 2 blocks/CU (r6 fixed) ----
// C[M,N] = A[M,K] * Bt[N,K]^T + bias
// 256 threads = 4 waves (2x2), per-wave 64x64 output, 16 MFMA/K-tile/wave.
// LDS: 4 bufs x 16KB {A 8K | B 8K}. Banking fix vs r6: two global rows packed
// per 128B LDS row; slot = ((row&1)*4 + chunk) ^ ((row>>1)&7). Per 16-lane
// group each 16B slot-column is hit exactly 2x (uniform -> conflict-free,
// same property as the r3-proven pattern). Staged via pre-swizzled global
// source (m173): writer at linear slot s of LDS-row R fetches global chunk
// g = s ^ (R&7) -> (row = 2R + (g>>2), elemoff = (g&3)*8).
// Ring ledger (r6, verified): stage t+3 during t; vmcnt(8) drains t+1's 4
// loads (12 outstanding); buf[t] was ensured at t-1. Tail: 4, then 0.
// 2 blocks/CU (64KB LDS, <=128 VGPR): sibling block's MFMA covers this
// block's barrier/read segments.
__global__ __launch_bounds__(256, 2) void gemm128(
    const unsigned short* __restrict__ A,   // [4096][4096] bf16
    const unsigned short* __restrict__ B,   // [32000][4096] bf16
    const float* __restrict__ bias,         // [32000]
    float* __restrict__ C)                  // [4096][32000] f32
{
    __shared__ __attribute__((aligned(16))) unsigned short lds[4][8192];

    const int tid = threadIdx.x;
    const int bid = blockIdx.x;
    // Locality: xcd owns 4 M-bands, 2 at a time (A 2MB L2-resident);
    // nt swept time-synced across XCDs -> B panel HBM-fetched ~2x total.
    const int xcd = bid & 7;
    int j = bid >> 3;                        // 0..999
    const int j2 = (j >= 500) ? 1 : 0;
    j -= j2 * 500;                           // 0..499
    const int mt = xcd * 4 + j2 * 2 + (j & 1);  // 32 M-tiles of 128
    const int nt = j >> 1;                      // 250 N-tiles of 128
    const long m0 = (long)mt * 128;
    const long n0 = (long)nt * 128;

    const int wid = tid >> 6, lane = tid & 63;
    const int wr = wid >> 1, wc = wid & 1;     // 2 x 2 waves
    const int lr = lane & 15, lk = lane >> 4;  // frag row, k-group (chunk)

    // frag read bases: slot = ((lr&1)*4 | lk) ^ ((lr>>1)&7); R&7 == (lr>>1)&7
    // for every frag row (rows step by 16 -> R steps by 8).
    const int s_lane = (((lr & 1) << 2) | lk) ^ ((lr >> 1) & 7);
    const unsigned short* pA = &lds[0][0] + wr * 2048 + (lr >> 1) * 64 + s_lane * 8;
    const unsigned short* pB = &lds[0][0] + 4096 + wc * 2048 + (lr >> 1) * 64 + s_lane * 8;
    #define LDA(mi, BUF) (*(const bf16x8*)(pA + (mi) * 512 + (BUF) * 8192))
    #define LDB(nj, BUF) (*(const bf16x8*)(pB + (nj) * 512 + (BUF) * 8192))

    // staging: thread -> slots {tid, 256+tid} per region; g = s ^ (R&7)
    const int g = (tid & 7) ^ ((tid >> 3) & 7);
    const int srow = 2 * (tid >> 3) + (g >> 2);   // 0..63
    const int scol = (g & 3) * 8;                 // elem offset in k
    const char* Ab = (const char*)(A + m0 * K_DIM);
    const char* Bb = (const char*)(B + n0 * K_DIM);
    unsigned int a0 = (unsigned)(srow * K_DIM + scol) * 2u;
    unsigned int a1 = a0 + 64u * K_DIM * 2u;      // rows +64

    #define ST(BUF) do {                                   \
        char* _l = (char*)&lds[(BUF)][0] + tid * 16;       \
        load16_to_lds(Ab + a0, _l);                        \
        load16_to_lds(Ab + a1, _l + 4096);                 \
        load16_to_lds(Bb + a0, _l + 8192);                 \
        load16_to_lds(Bb + a1, _l + 12288);                \
        a0 += 64; a1 += 64; } while (0)

    f32x4 acc[4][4];
    #pragma unroll
    for (int i = 0; i < 4; ++i)
        #pragma unroll
        for (int jn = 0; jn < 4; ++jn)
            acc[i][jn] = (f32x4){0.f, 0.f, 0.f, 0.f};

    // prologue: stage tiles 0,1,2 (12 loads); drain tile0; sync
    ST(0); ST(1); ST(2);
    VMCNT8();
    BAR();

    auto body = [&](auto bufc, int t) {
        constexpr int BUF = decltype(bufc)::v;
        bf16x8 af[4], bf[4];
        #pragma unroll
        for (int mi = 0; mi < 4; ++mi) af[mi] = LDA(mi, BUF);
        #pragma unroll
        for (int nj = 0; nj < 4; ++nj) bf[nj] = LDB(nj, BUF);
        if (t + 3 < NKT) ST((BUF + 3) & 3);
        if (t < NKT - 3)       { VMCNT8(); }
        else if (t == NKT - 3) { VMCNT4(); }
        else                   { VMCNT0(); }
        BAR();
        __builtin_amdgcn_s_setprio(1);
        #pragma unroll
        for (int mi = 0; mi < 4; ++mi)
            #pragma unroll
            for (int nj = 0; nj < 4; ++nj)
                acc[mi][nj] = __builtin_amdgcn_mfma_f32_16x16x32_bf16(
                    af[mi], bf[nj], acc[mi][nj], 0, 0, 0);
        __builtin_amdgcn_s_setprio(0);
        BAR();
    };

    for (int t = 0; t < NKT; t += 4) {
        body(IC<0>{}, t);
        body(IC<1>{}, t + 1);
        body(IC<2>{}, t + 2);
        body(IC<3>{}, t + 3);
    }
    #undef LDA
    #undef LDB
    #undef ST

    // epilogue: C/D layout col = lane&15 (lr), row = lk*4 + reg; nontemporal
    #pragma unroll
    for (int nj = 0; nj < 4; ++nj) {
        const long col = n0 + wc * 64 + nj * 16 + lr;
        const float bs = bias[col];
        #pragma unroll
        for (int mi = 0; mi < 4; ++mi) {
            const long row = m0 + wr * 64 + mi * 16 + lk * 4;
            #pragma unroll
            for (int r = 0; r < 4; ++r)
                __builtin_nontemporal_store(acc[mi][nj][r] + bs,
                                            &C[(row + r) * (long)N_DIM + col]);
        }
    }
}

// ---- emergency fallback if ws too small: naive fp32 (slow but correct) ----
__global__ void naive_out(const float* __restrict__ x, const float* __restrict__ w,
                          const float* __restrict__ b, float* __restrict__ out) {
    long idx = (long)blockIdx.x * 256 + threadIdx.x;
    if (idx >= (long)M_DIM * N_DIM) return;
    long m = idx / N_DIM;
    int v = (int)(idx - m * N_DIM);
    float s = 0.f;
    for (int h = 0; h < NHEAD; ++h) {
        const float* xr = x + m * K_DIM + h * DMODEL;
        const float* wr = w + ((long)h * DVOCAB + v) * DMODEL;
        float ps = 0.f;
        for (int d = 0; d < DMODEL; ++d) ps += xr[d] * wr[d];
        s += ps + b[h * DVOCAB + v];
    }
    out[idx] = s;
}

extern "C" void kernel_launch(void* const* d_in, const int* in_sizes, int n_in,
                              void* d_out, int out_size, void* d_ws, size_t ws_size,
                              hipStream_t stream) {
    const float* x = (const float*)d_in[0];   // [8,512,8,512]
    const float* w = (const float*)d_in[1];   // [8,32000,512]
    const float* b = (const float*)d_in[2];   // [8,32000]
    float* out = (float*)d_out;               // [8,512,32000]

    const size_t xbf_bytes = (size_t)M_DIM * K_DIM * 2;
    const size_t wbf_bytes = (size_t)N_DIM * K_DIM * 2;
    const size_t bs_bytes  = (size_t)N_DIM * 4;
    const size_t need = xbf_bytes + wbf_bytes + bs_bytes;

    if (ws_size < need) {
        long total = (long)M_DIM * N_DIM;
        int blocks = (int)((total + 255) / 256);
        naive_out<<<blocks, 256, 0, stream>>>(x, w, b, out);
        return;
    }

    unsigned short* xbf = (unsigned short*)d_ws;
    unsigned short* wbf = (unsigned short*)((char*)d_ws + xbf_bytes);
    float* bsum = (float*)((char*)d_ws + xbf_bytes + wbf_bytes);

    cvt_x<<<8192, 256, 0, stream>>>(x, xbf);
    cvt_w<<<64000, 256, 0, stream>>>(w, wbf);
    bias_red<<<125, 256, 0, stream>>>(b, bsum);
    gemm128<<<8000, 256, 0, stream>>>(xbf, wbf, bsum, out);  // 32 x 250 tiles
}

// Round 12
// 1078.646 us; speedup vs baseline: 1.3287x; 1.3287x over previous
//
#include <hip/hip_runtime.h>
#include <hip/hip_bf16.h>
#include <stdint.h>

// Problem constants
#define NHEAD 8
#define DMODEL 512
#define DVOCAB 32000
#define M_DIM 4096            // B*P
#define K_DIM 4096            // NHEAD*DMODEL
#define N_DIM 32000           // DVOCAB
#define NT    64              // K_DIM / 64 k-tiles

typedef short bf16x8 __attribute__((ext_vector_type(8)));
typedef float f32x4 __attribute__((ext_vector_type(4)));
typedef unsigned short ushort8 __attribute__((ext_vector_type(8)));

template <int V> struct IC { static constexpr int v = V; };

__device__ __forceinline__ unsigned short f2bf(float f) {
    unsigned int u = __builtin_bit_cast(unsigned int, f);
    u = (u + 0x7fffu + ((u >> 16) & 1u)) >> 16;   // RNE (inputs are finite)
    return (unsigned short)u;
}

__device__ __forceinline__ void load16_to_lds(const void* g, void* l) {
    __builtin_amdgcn_global_load_lds(
        (const __attribute__((address_space(1))) unsigned int*)g,
        (__attribute__((address_space(3))) unsigned int*)l, 16, 0, 0);
}

// ---- x [4096][4096] f32 -> bf16, 8 elems/thread ----
__global__ void cvt_x(const float* __restrict__ in, unsigned short* __restrict__ out) {
    long t = (long)blockIdx.x * 256 + threadIdx.x;
    const float4* s = (const float4*)in + t * 2;
    float4 a = s[0], b = s[1];
    ushort8 o;
    o[0] = f2bf(a.x); o[1] = f2bf(a.y); o[2] = f2bf(a.z); o[3] = f2bf(a.w);
    o[4] = f2bf(b.x); o[5] = f2bf(b.y); o[6] = f2bf(b.z); o[7] = f2bf(b.w);
    *(ushort8*)(out + t * 8) = o;
}

// ---- W [H][V][D] f32 -> Wb [V][H*D] bf16 (B^T layout), 8 elems/thread ----
__global__ void cvt_w(const float* __restrict__ in, unsigned short* __restrict__ out) {
    int t = blockIdx.x * 256 + threadIdx.x;
    int d8 = t & 63;
    int hv = t >> 6;
    int h = hv / DVOCAB;
    int v = hv - h * DVOCAB;
    const float4* s = (const float4*)(in + (long)hv * DMODEL + d8 * 8);
    float4 a = s[0], b = s[1];
    ushort8 o;
    o[0] = f2bf(a.x); o[1] = f2bf(a.y); o[2] = f2bf(a.z); o[3] = f2bf(a.w);
    o[4] = f2bf(b.x); o[5] = f2bf(b.y); o[6] = f2bf(b.z); o[7] = f2bf(b.w);
    *(ushort8*)(out + (long)v * K_DIM + h * DMODEL + d8 * 8) = o;
}

// ---- bias [H][V] -> bsum [V] ----
__global__ void bias_red(const float* __restrict__ b, float* __restrict__ out) {
    int v = blockIdx.x * 256 + threadIdx.x;
    if (v >= DVOCAB) return;
    float s = 0.f;
    #pragma unroll
    for (int h = 0; h < NHEAD; ++h) s += b[h * DVOCAB + v];
    out[v] = s;
}

#define BAR()    __builtin_amdgcn_s_barrier()
#define VMCNT6() asm volatile("s_waitcnt vmcnt(6)" ::: "memory")
#define VMCNT0() asm volatile("s_waitcnt vmcnt(0)" ::: "memory")

// ---- bf16 GEMM, 256x256 tile, BK=64, 8-phase schedule, compiler lgkm ----
// (r10 kernel — best verified: GEMM ~1020 us, MfmaUtil ~48%, 0 conflicts)
// C[M,N] = A[M,K] * Bt[N,K]^T + bias
// ds_reads are compiler-visible: scheduler emits counted lgkmcnt interleaved
// in the MFMA cluster. Every read is consumed by the same phase's MFMA
// (data dep -> complete before the phase-ending BAR), so each region's stage
// happens >=1 barrier after its last read. VMCNT keeps "memory" clobber.
__global__ __launch_bounds__(512, 2) void gemm256(
    const unsigned short* __restrict__ A,   // [4096][4096] bf16
    const unsigned short* __restrict__ B,   // [32000][4096] bf16
    const float* __restrict__ bias,         // [32000]
    float* __restrict__ C)                  // [4096][32000] f32
{
    __shared__ __attribute__((aligned(16))) unsigned short lds[2][2][2][8192];

    const int tid = threadIdx.x;
    const int bid = blockIdx.x;
    // Locality swizzle (r8-proven: FETCH 1.5->1.16 GB): XCD owns 2 M-bands,
    // nt swept time-synced across XCDs -> B-panel fetched ~once.
    const int xcd = bid & 7, j = bid >> 3;   // j in 0..249
    const int mt = xcd * 2 + (j & 1);        // 16 M-tiles
    const int nt = j >> 1;                   // 125 N-tiles
    const long m0 = (long)mt * 256;
    const long n0 = (long)nt * 256;

    const int wid = tid >> 6, lane = tid & 63;
    const int wr = wid >> 2, wc = wid & 3;     // 2 x 4 waves
    const int lr = lane & 15, lk = lane >> 4;
    const int swz = lr & 7;                    // row&7 == lr&7 for all frag rows

    // ds_read base pointers: 4 VGPRs, everything else immediate offsets
    const unsigned short* pA[2];
    const unsigned short* pB[2];
    #pragma unroll
    for (int ks = 0; ks < 2; ++ks) {
        const int ch = ((ks << 2) | lk) ^ swz;
        pA[ks] = &lds[0][0][0][0] + (wr * 64 + lr) * 64 + ch * 8;
        pB[ks] = &lds[1][0][0][0] + (wc * 32 + lr) * 64 + ch * 8;
    }
    // frag read: [rows of 16][half][buf] as compile-time immediates (<64KiB)
    #define LDA(mi, ks, HALF, CURB) \
        (*(const bf16x8*)(pA[ks] + (mi) * 1024 + (HALF) * 16384 + (CURB) * 8192))
    #define LDB(nj, ks, HALF, CURB) \
        (*(const bf16x8*)(pB[ks] + (nj) * 1024 + (HALF) * 16384 + (CURB) * 8192))

    // staging: per-lane 32-bit byte offsets off uniform bases, advanced +128B/use
    const char* Ab = (const char*)(A + m0 * K_DIM);
    const char* Bb = (const char*)(B + n0 * K_DIM);
    const int row0 = tid >> 3,         c0 = (tid & 7) ^ (row0 & 7);
    const int row1 = (512 + tid) >> 3, c1 = ((512 + tid) & 7) ^ (row1 & 7);
    unsigned int a00 = (unsigned)(row0 * K_DIM + c0 * 8) * 2u;
    unsigned int a01 = (unsigned)(row1 * K_DIM + c1 * 8) * 2u;
    unsigned int a10 = (unsigned)((128 + row0) * K_DIM + c0 * 8) * 2u;
    unsigned int a11 = (unsigned)((128 + row1) * K_DIM + c1 * 8) * 2u;
    unsigned int b00 = a00, b01 = a01, b10 = a10, b11 = a11;

    #define ST_A0(CURB) do { \
        load16_to_lds(Ab + a00, (char*)&lds[0][0][(CURB)][0] + tid * 16); \
        load16_to_lds(Ab + a01, (char*)&lds[0][0][(CURB)][0] + 8192 + tid * 16); \
        a00 += 128; a01 += 128; } while (0)
    #define ST_A1(CURB) do { \
        load16_to_lds(Ab + a10, (char*)&lds[0][1][(CURB)][0] + tid * 16); \
        load16_to_lds(Ab + a11, (char*)&lds[0][1][(CURB)][0] + 8192 + tid * 16); \
        a10 += 128; a11 += 128; } while (0)
    #define ST_B0(CURB) do { \
        load16_to_lds(Bb + b00, (char*)&lds[1][0][(CURB)][0] + tid * 16); \
        load16_to_lds(Bb + b01, (char*)&lds[1][0][(CURB)][0] + 8192 + tid * 16); \
        b00 += 128; b01 += 128; } while (0)
    #define ST_B1(CURB) do { \
        load16_to_lds(Bb + b10, (char*)&lds[1][1][(CURB)][0] + tid * 16); \
        load16_to_lds(Bb + b11, (char*)&lds[1][1][(CURB)][0] + 8192 + tid * 16); \
        b10 += 128; b11 += 128; } while (0)

    // MFMA quad: 16 MFMAs, ks outermost (dependent same-acc pairs 8 apart)
    #define MFQUAD(AF, BF, MO, NO) do {                                        \
        _Pragma("unroll")                                                      \
        for (int ks = 0; ks < 2; ++ks)                                         \
            _Pragma("unroll")                                                  \
            for (int mi = 0; mi < 4; ++mi)                                     \
                _Pragma("unroll")                                              \
                for (int nj = 0; nj < 2; ++nj)                                 \
                    acc[(MO) + mi][(NO) + nj] =                                \
                        __builtin_amdgcn_mfma_f32_16x16x32_bf16(               \
                            AF[mi][ks], BF[nj][ks], acc[(MO) + mi][(NO) + nj], \
                            0, 0, 0);                                          \
    } while (0)

    f32x4 acc[8][4];
    #pragma unroll
    for (int i = 0; i < 8; ++i)
        #pragma unroll
        for (int jn = 0; jn < 4; ++jn)
            acc[i][jn] = (f32x4){0.f, 0.f, 0.f, 0.f};

    bf16x8 af[4][2], bf0[2][2], bf1[2][2];

    // prologue: tile0 fully + tile1 {Ah0,Bh0,Bh1}; 14 loads, keep 6 in flight
    ST_A0(0); ST_B0(0); ST_B1(0); ST_A1(0);
    ST_A0(1); ST_B0(1); ST_B1(1);
    VMCNT6();
    BAR();

    auto body = [&](auto curc, int t) {
        constexpr int CUR = decltype(curc)::v;

        // ---- P1: read A-h0(8) + B-h0(4); stage (t+1).Ah1; q00
        #pragma unroll
        for (int mi = 0; mi < 4; ++mi) {
            af[mi][0] = LDA(mi, 0, 0, CUR);
            af[mi][1] = LDA(mi, 1, 0, CUR);
        }
        #pragma unroll
        for (int nj = 0; nj < 2; ++nj) {
            bf0[nj][0] = LDB(nj, 0, 0, CUR);
            bf0[nj][1] = LDB(nj, 1, 0, CUR);
        }
        if (t + 1 < NT) ST_A1(CUR ^ 1);
        BAR();
        __builtin_amdgcn_s_setprio(1);
        MFQUAD(af, bf0, 0, 0);
        __builtin_amdgcn_s_setprio(0);
        BAR();

        // ---- P2: read B-h1(4); stage (t+2).Ah0; q01
        #pragma unroll
        for (int nj = 0; nj < 2; ++nj) {
            bf1[nj][0] = LDB(nj, 0, 1, CUR);
            bf1[nj][1] = LDB(nj, 1, 1, CUR);
        }
        if (t + 2 < NT) ST_A0(CUR);
        BAR();
        __builtin_amdgcn_s_setprio(1);
        MFQUAD(af, bf1, 0, 2);
        __builtin_amdgcn_s_setprio(0);
        BAR();

        // ---- P3: read A-h1(8); stage (t+2).Bh0; q10
        #pragma unroll
        for (int mi = 0; mi < 4; ++mi) {
            af[mi][0] = LDA(mi, 0, 1, CUR);
            af[mi][1] = LDA(mi, 1, 1, CUR);
        }
        if (t + 2 < NT) ST_B0(CUR);
        BAR();
        __builtin_amdgcn_s_setprio(1);
        MFQUAD(af, bf0, 4, 0);
        __builtin_amdgcn_s_setprio(0);
        BAR();

        // ---- P4: stage (t+2).Bh1; counted vmcnt; q11
        if (t + 2 < NT) ST_B1(CUR);
        if (t < NT - 2) { VMCNT6(); } else { VMCNT0(); }
        BAR();
        __builtin_amdgcn_s_setprio(1);
        MFQUAD(af, bf1, 4, 2);
        __builtin_amdgcn_s_setprio(0);
        BAR();
    };

    for (int t = 0; t < NT; t += 2) {
        body(IC<0>{}, t);
        body(IC<1>{}, t + 1);
    }
    #undef LDA
    #undef LDB
    #undef ST_A0
    #undef ST_A1
    #undef ST_B0
    #undef ST_B1
    #undef MFQUAD

    // epilogue: C/D layout col = lane&15 (lr), row = lk*4 + reg; nontemporal
    #pragma unroll
    for (int nj = 0; nj < 4; ++nj) {
        const long col = n0 + (nj >> 1) * 128 + wc * 32 + (nj & 1) * 16 + lr;
        const float bs = bias[col];
        #pragma unroll
        for (int mi = 0; mi < 8; ++mi) {
            const long row = m0 + (mi >> 2) * 128 + wr * 64 + (mi & 3) * 16 + lk * 4;
            #pragma unroll
            for (int r = 0; r < 4; ++r)
                __builtin_nontemporal_store(acc[mi][nj][r] + bs,
                                            &C[(row + r) * (long)N_DIM + col]);
        }
    }
}

// ---- emergency fallback if ws too small: naive fp32 (slow but correct) ----
__global__ void naive_out(const float* __restrict__ x, const float* __restrict__ w,
                          const float* __restrict__ b, float* __restrict__ out) {
    long idx = (long)blockIdx.x * 256 + threadIdx.x;
    if (idx >= (long)M_DIM * N_DIM) return;
    long m = idx / N_DIM;
    int v = (int)(idx - m * N_DIM);
    float s = 0.f;
    for (int h = 0; h < NHEAD; ++h) {
        const float* xr = x + m * K_DIM + h * DMODEL;
        const float* wr = w + ((long)h * DVOCAB + v) * DMODEL;
        float ps = 0.f;
        for (int d = 0; d < DMODEL; ++d) ps += xr[d] * wr[d];
        s += ps + b[h * DVOCAB + v];
    }
    out[idx] = s;
}

extern "C" void kernel_launch(void* const* d_in, const int* in_sizes, int n_in,
                              void* d_out, int out_size, void* d_ws, size_t ws_size,
                              hipStream_t stream) {
    const float* x = (const float*)d_in[0];   // [8,512,8,512]
    const float* w = (const float*)d_in[1];   // [8,32000,512]
    const float* b = (const float*)d_in[2];   // [8,32000]
    float* out = (float*)d_out;               // [8,512,32000]

    const size_t xbf_bytes = (size_t)M_DIM * K_DIM * 2;
    const size_t wbf_bytes = (size_t)N_DIM * K_DIM * 2;
    const size_t bs_bytes  = (size_t)N_DIM * 4;
    const size_t need = xbf_bytes + wbf_bytes + bs_bytes;

    if (ws_size < need) {
        long total = (long)M_DIM * N_DIM;
        int blocks = (int)((total + 255) / 256);
        naive_out<<<blocks, 256, 0, stream>>>(x, w, b, out);
        return;
    }

    unsigned short* xbf = (unsigned short*)d_ws;
    unsigned short* wbf = (unsigned short*)((char*)d_ws + xbf_bytes);
    float* bsum = (float*)((char*)d_ws + xbf_bytes + wbf_bytes);

    cvt_x<<<8192, 256, 0, stream>>>(x, xbf);
    cvt_w<<<64000, 256, 0, stream>>>(w, wbf);
    bias_red<<<125, 256, 0, stream>>>(b, bsum);
    gemm256<<<2000, 512, 0, stream>>>(xbf, wbf, bsum, out);  // 16 x 125 tiles
}

// Round 13
// 1065.606 us; speedup vs baseline: 1.3449x; 1.0122x over previous
//
#include <hip/hip_runtime.h>
#include <hip/hip_bf16.h>
#include <stdint.h>

// Problem constants
#define NHEAD 8
#define DMODEL 512
#define DVOCAB 32000
#define M_DIM 4096            // B*P
#define K_DIM 4096            // NHEAD*DMODEL
#define N_DIM 32000           // DVOCAB
#define NT    64              // K_DIM / 64 k-tiles

typedef short bf16x8 __attribute__((ext_vector_type(8)));
typedef float f32x4 __attribute__((ext_vector_type(4)));
typedef unsigned short ushort8 __attribute__((ext_vector_type(8)));

template <int V> struct IC { static constexpr int v = V; };

__device__ __forceinline__ unsigned short f2bf(float f) {
    unsigned int u = __builtin_bit_cast(unsigned int, f);
    u = (u + 0x7fffu + ((u >> 16) & 1u)) >> 16;   // RNE (inputs are finite)
    return (unsigned short)u;
}

__device__ __forceinline__ void load16_to_lds(const void* g, void* l) {
    __builtin_amdgcn_global_load_lds(
        (const __attribute__((address_space(1))) unsigned int*)g,
        (__attribute__((address_space(3))) unsigned int*)l, 16, 0, 0);
}

// ---- x [4096][4096] f32 -> bf16, 8 elems/thread ----
__global__ void cvt_x(const float* __restrict__ in, unsigned short* __restrict__ out) {
    long t = (long)blockIdx.x * 256 + threadIdx.x;
    const float4* s = (const float4*)in + t * 2;
    float4 a = s[0], b = s[1];
    ushort8 o;
    o[0] = f2bf(a.x); o[1] = f2bf(a.y); o[2] = f2bf(a.z); o[3] = f2bf(a.w);
    o[4] = f2bf(b.x); o[5] = f2bf(b.y); o[6] = f2bf(b.z); o[7] = f2bf(b.w);
    *(ushort8*)(out + t * 8) = o;
}

// ---- W [H][V][D] f32 -> Wb [V][H*D] bf16 (B^T layout), 8 elems/thread ----
__global__ void cvt_w(const float* __restrict__ in, unsigned short* __restrict__ out) {
    int t = blockIdx.x * 256 + threadIdx.x;
    int d8 = t & 63;
    int hv = t >> 6;
    int h = hv / DVOCAB;
    int v = hv - h * DVOCAB;
    const float4* s = (const float4*)(in + (long)hv * DMODEL + d8 * 8);
    float4 a = s[0], b = s[1];
    ushort8 o;
    o[0] = f2bf(a.x); o[1] = f2bf(a.y); o[2] = f2bf(a.z); o[3] = f2bf(a.w);
    o[4] = f2bf(b.x); o[5] = f2bf(b.y); o[6] = f2bf(b.z); o[7] = f2bf(b.w);
    *(ushort8*)(out + (long)v * K_DIM + h * DMODEL + d8 * 8) = o;
}

// ---- bias [H][V] -> bsum [V] ----
__global__ void bias_red(const float* __restrict__ b, float* __restrict__ out) {
    int v = blockIdx.x * 256 + threadIdx.x;
    if (v >= DVOCAB) return;
    float s = 0.f;
    #pragma unroll
    for (int h = 0; h < NHEAD; ++h) s += b[h * DVOCAB + v];
    out[v] = s;
}

#define BAR()    __builtin_amdgcn_s_barrier()
#define VMCNT6() asm volatile("s_waitcnt vmcnt(6)" ::: "memory")
#define VMCNT0() asm volatile("s_waitcnt vmcnt(0)" ::: "memory")

// ---- bf16 GEMM, 256x256 tile, BK=64, 3-phase (P3+P4 merged), compiler lgkm ----
// C[M,N] = A[M,K] * Bt[N,K]^T + bias
// r10 skeleton with P3/P4 merged: 6 barriers/K-tile instead of 8; the 32-MFMA
// cluster (1240 cyc/SIMD) covers the 8-read drain (512 cyc CU-wide).
// Hazard ledger (per tile t, CUR=t&1):
//  - (t+1).A1 -> buf^1 @P1: A1[buf^1] last ds_read at t-1.P3' (afH), complete
//    before t-1.P3' MFMA -> before its trailing BAR ✓
//  - (t+2).A0 -> buf[CUR] @P2: A0 last read t.P1 -> P1-end BAR ✓
//  - (t+2).B0,B1 -> buf[CUR] @P3': B0 last read t.P1, B1 last read t.P2 ✓
//  - vmcnt(6) @P3': newer-than-(t+1).A1 = (t+2).{A0,B0,B1} = 6 -> tile t+1
//    fully resident before next-P1 reads buf^1 (BAR orders all waves) ✓
//  - tails: t >= NT-2 -> vmcnt(0) ✓
__global__ __launch_bounds__(512, 2) void gemm256(
    const unsigned short* __restrict__ A,   // [4096][4096] bf16
    const unsigned short* __restrict__ B,   // [32000][4096] bf16
    const float* __restrict__ bias,         // [32000]
    float* __restrict__ C)                  // [4096][32000] f32
{
    __shared__ __attribute__((aligned(16))) unsigned short lds[2][2][2][8192];

    const int tid = threadIdx.x;
    const int bid = blockIdx.x;
    // Locality swizzle (r8-proven): XCD owns 2 M-bands; nt time-synced sweep.
    const int xcd = bid & 7, j = bid >> 3;   // j in 0..249
    const int mt = xcd * 2 + (j & 1);        // 16 M-tiles
    const int nt = j >> 1;                   // 125 N-tiles
    const long m0 = (long)mt * 256;
    const long n0 = (long)nt * 256;

    const int wid = tid >> 6, lane = tid & 63;
    const int wr = wid >> 2, wc = wid & 3;     // 2 x 4 waves
    const int lr = lane & 15, lk = lane >> 4;
    const int swz = lr & 7;                    // row&7 == lr&7 for all frag rows

    // ds_read base pointers: 4 VGPRs, everything else immediate offsets
    const unsigned short* pA[2];
    const unsigned short* pB[2];
    #pragma unroll
    for (int ks = 0; ks < 2; ++ks) {
        const int ch = ((ks << 2) | lk) ^ swz;
        pA[ks] = &lds[0][0][0][0] + (wr * 64 + lr) * 64 + ch * 8;
        pB[ks] = &lds[1][0][0][0] + (wc * 32 + lr) * 64 + ch * 8;
    }
    // frag read: [rows of 16][half][buf] as compile-time immediates (<64KiB)
    #define LDA(mi, ks, HALF, CURB) \
        (*(const bf16x8*)(pA[ks] + (mi) * 1024 + (HALF) * 16384 + (CURB) * 8192))
    #define LDB(nj, ks, HALF, CURB) \
        (*(const bf16x8*)(pB[ks] + (nj) * 1024 + (HALF) * 16384 + (CURB) * 8192))

    // staging: per-lane 32-bit byte offsets off uniform bases, advanced +128B/use
    const char* Ab = (const char*)(A + m0 * K_DIM);
    const char* Bb = (const char*)(B + n0 * K_DIM);
    const int row0 = tid >> 3,         c0 = (tid & 7) ^ (row0 & 7);
    const int row1 = (512 + tid) >> 3, c1 = ((512 + tid) & 7) ^ (row1 & 7);
    unsigned int a00 = (unsigned)(row0 * K_DIM + c0 * 8) * 2u;
    unsigned int a01 = (unsigned)(row1 * K_DIM + c1 * 8) * 2u;
    unsigned int a10 = (unsigned)((128 + row0) * K_DIM + c0 * 8) * 2u;
    unsigned int a11 = (unsigned)((128 + row1) * K_DIM + c1 * 8) * 2u;
    unsigned int b00 = a00, b01 = a01, b10 = a10, b11 = a11;

    #define ST_A0(CURB) do { \
        load16_to_lds(Ab + a00, (char*)&lds[0][0][(CURB)][0] + tid * 16); \
        load16_to_lds(Ab + a01, (char*)&lds[0][0][(CURB)][0] + 8192 + tid * 16); \
        a00 += 128; a01 += 128; } while (0)
    #define ST_A1(CURB) do { \
        load16_to_lds(Ab + a10, (char*)&lds[0][1][(CURB)][0] + tid * 16); \
        load16_to_lds(Ab + a11, (char*)&lds[0][1][(CURB)][0] + 8192 + tid * 16); \
        a10 += 128; a11 += 128; } while (0)
    #define ST_B0(CURB) do { \
        load16_to_lds(Bb + b00, (char*)&lds[1][0][(CURB)][0] + tid * 16); \
        load16_to_lds(Bb + b01, (char*)&lds[1][0][(CURB)][0] + 8192 + tid * 16); \
        b00 += 128; b01 += 128; } while (0)
    #define ST_B1(CURB) do { \
        load16_to_lds(Bb + b10, (char*)&lds[1][1][(CURB)][0] + tid * 16); \
        load16_to_lds(Bb + b11, (char*)&lds[1][1][(CURB)][0] + 8192 + tid * 16); \
        b10 += 128; b11 += 128; } while (0)

    // MFMA quad: 16 MFMAs, ks outermost (dependent same-acc pairs 8 apart)
    #define MFQUAD(AF, BF, MO, NO) do {                                        \
        _Pragma("unroll")                                                      \
        for (int ks = 0; ks < 2; ++ks)                                         \
            _Pragma("unroll")                                                  \
            for (int mi = 0; mi < 4; ++mi)                                     \
                _Pragma("unroll")                                              \
                for (int nj = 0; nj < 2; ++nj)                                 \
                    acc[(MO) + mi][(NO) + nj] =                                \
                        __builtin_amdgcn_mfma_f32_16x16x32_bf16(               \
                            AF[mi][ks], BF[nj][ks], acc[(MO) + mi][(NO) + nj], \
                            0, 0, 0);                                          \
    } while (0)

    f32x4 acc[8][4];
    #pragma unroll
    for (int i = 0; i < 8; ++i)
        #pragma unroll
        for (int jn = 0; jn < 4; ++jn)
            acc[i][jn] = (f32x4){0.f, 0.f, 0.f, 0.f};

    bf16x8 af[4][2], bf0[2][2], bf1[2][2];

    // prologue: tile0 fully + tile1 {Ah0,Bh0,Bh1}; 14 loads, keep 6 in flight
    ST_A0(0); ST_B0(0); ST_B1(0); ST_A1(0);
    ST_A0(1); ST_B0(1); ST_B1(1);
    VMCNT6();
    BAR();

    auto body = [&](auto curc, int t) {
        constexpr int CUR = decltype(curc)::v;

        // ---- P1: read A-h0(8) + B-h0(4); stage (t+1).Ah1; q00
        #pragma unroll
        for (int mi = 0; mi < 4; ++mi) {
            af[mi][0] = LDA(mi, 0, 0, CUR);
            af[mi][1] = LDA(mi, 1, 0, CUR);
        }
        #pragma unroll
        for (int nj = 0; nj < 2; ++nj) {
            bf0[nj][0] = LDB(nj, 0, 0, CUR);
            bf0[nj][1] = LDB(nj, 1, 0, CUR);
        }
        if (t + 1 < NT) ST_A1(CUR ^ 1);
        BAR();
        __builtin_amdgcn_s_setprio(1);
        MFQUAD(af, bf0, 0, 0);
        __builtin_amdgcn_s_setprio(0);
        BAR();

        // ---- P2: read B-h1(4); stage (t+2).Ah0; q01
        #pragma unroll
        for (int nj = 0; nj < 2; ++nj) {
            bf1[nj][0] = LDB(nj, 0, 1, CUR);
            bf1[nj][1] = LDB(nj, 1, 1, CUR);
        }
        if (t + 2 < NT) ST_A0(CUR);
        BAR();
        __builtin_amdgcn_s_setprio(1);
        MFQUAD(af, bf1, 0, 2);
        __builtin_amdgcn_s_setprio(0);
        BAR();

        // ---- P3' (merged P3+P4): read A-h1(8); stage (t+2).Bh0 + (t+2).Bh1;
        //      counted vmcnt; q10 + q11 (32 MFMAs)
        #pragma unroll
        for (int mi = 0; mi < 4; ++mi) {
            af[mi][0] = LDA(mi, 0, 1, CUR);
            af[mi][1] = LDA(mi, 1, 1, CUR);
        }
        if (t + 2 < NT) { ST_B0(CUR); ST_B1(CUR); }
        if (t < NT - 2) { VMCNT6(); } else { VMCNT0(); }
        BAR();
        __builtin_amdgcn_s_setprio(1);
        MFQUAD(af, bf0, 4, 0);
        MFQUAD(af, bf1, 4, 2);
        __builtin_amdgcn_s_setprio(0);
        BAR();
    };

    for (int t = 0; t < NT; t += 2) {
        body(IC<0>{}, t);
        body(IC<1>{}, t + 1);
    }
    #undef LDA
    #undef LDB
    #undef ST_A0
    #undef ST_A1
    #undef ST_B0
    #undef ST_B1
    #undef MFQUAD

    // epilogue: C/D layout col = lane&15 (lr), row = lk*4 + reg; nontemporal
    #pragma unroll
    for (int nj = 0; nj < 4; ++nj) {
        const long col = n0 + (nj >> 1) * 128 + wc * 32 + (nj & 1) * 16 + lr;
        const float bs = bias[col];
        #pragma unroll
        for (int mi = 0; mi < 8; ++mi) {
            const long row = m0 + (mi >> 2) * 128 + wr * 64 + (mi & 3) * 16 + lk * 4;
            #pragma unroll
            for (int r = 0; r < 4; ++r)
                __builtin_nontemporal_store(acc[mi][nj][r] + bs,
                                            &C[(row + r) * (long)N_DIM + col]);
        }
    }
}

// ---- emergency fallback if ws too small: naive fp32 (slow but correct) ----
__global__ void naive_out(const float* __restrict__ x, const float* __restrict__ w,
                          const float* __restrict__ b, float* __restrict__ out) {
    long idx = (long)blockIdx.x * 256 + threadIdx.x;
    if (idx >= (long)M_DIM * N_DIM) return;
    long m = idx / N_DIM;
    int v = (int)(idx - m * N_DIM);
    float s = 0.f;
    for (int h = 0; h < NHEAD; ++h) {
        const float* xr = x + m * K_DIM + h * DMODEL;
        const float* wr = w + ((long)h * DVOCAB + v) * DMODEL;
        float ps = 0.f;
        for (int d = 0; d < DMODEL; ++d) ps += xr[d] * wr[d];
        s += ps + b[h * DVOCAB + v];
    }
    out[idx] = s;
}

extern "C" void kernel_launch(void* const* d_in, const int* in_sizes, int n_in,
                              void* d_out, int out_size, void* d_ws, size_t ws_size,
                              hipStream_t stream) {
    const float* x = (const float*)d_in[0];   // [8,512,8,512]
    const float* w = (const float*)d_in[1];   // [8,32000,512]
    const float* b = (const float*)d_in[2];   // [8,32000]
    float* out = (float*)d_out;               // [8,512,32000]

    const size_t xbf_bytes = (size_t)M_DIM * K_DIM * 2;
    const size_t wbf_bytes = (size_t)N_DIM * K_DIM * 2;
    const size_t bs_bytes  = (size_t)N_DIM * 4;
    const size_t need = xbf_bytes + wbf_bytes + bs_bytes;

    if (ws_size < need) {
        long total = (long)M_DIM * N_DIM;
        int blocks = (int)((total + 255) / 256);
        naive_out<<<blocks, 256, 0, stream>>>(x, w, b, out);
        return;
    }

    unsigned short* xbf = (unsigned short*)d_ws;
    unsigned short* wbf = (unsigned short*)((char*)d_ws + xbf_bytes);
    float* bsum = (float*)((char*)d_ws + xbf_bytes + wbf_bytes);

    cvt_x<<<8192, 256, 0, stream>>>(x, xbf);
    cvt_w<<<64000, 256, 0, stream>>>(w, wbf);
    bias_red<<<125, 256, 0, stream>>>(b, bsum);
    gemm256<<<2000, 512, 0, stream>>>(xbf, wbf, bsum, out);  // 16 x 125 tiles
}